// Round 1
// baseline (52.318 us; speedup 1.0000x reference)
//
#include <hip/hip_runtime.h>

#define BB 16
#define NN 768
#define NBOND 6144
#define BOTOLF 0.001f

// LDS weight layout offsets (floats)
#define OFF_FM_WI 0     // 3x9  = 27
#define OFF_FM_BI 27    // 9
#define OFF_FM_W  36    // 5x9x9 = 405
#define OFF_FM_B  441   // 5x9 = 45
#define OFF_FM_WO 486   // 9x3 = 27
#define OFF_FM_BO 513   // 3
#define OFF_FE_WI 516   // 3x8 = 24
#define OFF_FE_BI 540   // 8
#define OFF_FE_W  548   // 5x8x8 = 320
#define OFF_FE_B  868   // 5x8 = 40
#define OFF_FE_WO 908   // 8x1 = 8
#define OFF_FE_BO 916   // 1
#define W_TOTAL   917

__device__ __forceinline__ float sigf(float z) {
    return 1.0f / (1.0f + __expf(-z));
}

// bop value + d(bop)/dr. bo2 passed as compile-time int (6,5,4).
__device__ __forceinline__ void bop_calc(float r, float bo1, float r0, int ibo2,
                                         float& bop, float& dbop_dr)
{
    float t = r / r0;
    float t2 = t * t;
    float p;
    if (ibo2 == 6)      p = t2 * t2 * t2;
    else if (ibo2 == 5) p = t2 * t2 * t;
    else                p = t2 * t2;
    float e = (1.0f + BOTOLF) * __expf(bo1 * p);
    // de/dr = e * bo1 * bo2 * t^(bo2-1) / r0 = e*bo1*bo2*p/r   (r = t*r0, r >= 1e-4)
    float de_dr = e * bo1 * (float)ibo2 * p / r;

    const float rmin = BOTOLF, rmax = 2.0f * BOTOLF;
    float T, dT;
    if (e > rmax) { T = 1.0f; dT = 0.0f; }
    else if (e > rmin) {
        const float rterm = -1.0e9f;           // 1/(rmin-rmax)^3
        float rd   = rmin - e;
        float trm1 = rmin + 2.0f * e - 3.0f * rmax;
        T  = rterm * rd * rd * trm1;
        dT = rterm * 2.0f * rd * (rd - trm1);
    } else { T = 0.0f; dT = 0.0f; }

    bop     = T * (e - BOTOLF);
    dbop_dr = (dT * (e - BOTOLF) + T) * de_dr;
}

__global__ __launch_bounds__(256) void reaxff_bond_kernel(
    const float* __restrict__ x, const float* __restrict__ cell, const float* __restrict__ rcell,
    const float* __restrict__ fm_wi, const float* __restrict__ fm_bi,
    const float* __restrict__ fm_w,  const float* __restrict__ fm_b,
    const float* __restrict__ fm_wo, const float* __restrict__ fm_bo,
    const float* __restrict__ fe_wi, const float* __restrict__ fe_bi,
    const float* __restrict__ fe_w,  const float* __restrict__ fe_b,
    const float* __restrict__ fe_wo, const float* __restrict__ fe_bo,
    const float* __restrict__ desi_p, const int* __restrict__ bdid,
    float* __restrict__ out)   // out[0..15] = E, out[16..] = force (B,N,3)
{
    __shared__ float w[W_TOTAL];
    __shared__ float esum[4];
    const int tid = threadIdx.x;

    // ---- stage weights to LDS ----
    {
        const float* srcs[12] = {fm_wi, fm_bi, fm_w, fm_b, fm_wo, fm_bo,
                                 fe_wi, fe_bi, fe_w, fe_b, fe_wo, fe_bo};
        const int lens[12] = {27, 9, 405, 45, 27, 3, 24, 8, 320, 40, 8, 1};
        int off = 0;
        for (int a = 0; a < 12; a++) {
            for (int i = tid; i < lens[a]; i += 256) w[off + i] = srcs[a][i];
            off += lens[a];
        }
    }
    __syncthreads();

    const int blocks_per_batch = NBOND / 256;          // 24
    const int b = blockIdx.x / blocks_per_batch;
    const int k = (blockIdx.x % blocks_per_batch) * 256 + tid;

    const int ai = bdid[k * 2 + 0];
    const int aj = bdid[k * 2 + 1];

    const float* cb = cell  + b * 9;
    const float* rb = rcell + b * 9;

    // u = x_i - x_j
    const float* xi = x + (size_t)(b * NN + ai) * 3;
    const float* xj = x + (size_t)(b * NN + aj) * 3;
    float u0 = xi[0] - xj[0];
    float u1 = xi[1] - xj[1];
    float u2 = xi[2] - xj[2];

    // f = u @ rcell
    float f0 = u0 * rb[0] + u1 * rb[3] + u2 * rb[6];
    float f1 = u0 * rb[1] + u1 * rb[4] + u2 * rb[7];
    float f2 = u0 * rb[2] + u1 * rb[5] + u2 * rb[8];
    // PBC wrap (matches reference's two sequential wheres)
    f0 = (f0 - 0.5f > 0.0f) ? f0 - 1.0f : f0;  f0 = (f0 + 0.5f < 0.0f) ? f0 + 1.0f : f0;
    f1 = (f1 - 0.5f > 0.0f) ? f1 - 1.0f : f1;  f1 = (f1 + 0.5f < 0.0f) ? f1 + 1.0f : f1;
    f2 = (f2 - 0.5f > 0.0f) ? f2 - 1.0f : f2;  f2 = (f2 + 0.5f < 0.0f) ? f2 + 1.0f : f2;
    // vr = f @ cell
    float v0 = f0 * cb[0] + f1 * cb[3] + f2 * cb[6];
    float v1 = f0 * cb[1] + f1 * cb[4] + f2 * cb[7];
    float v2 = f0 * cb[2] + f1 * cb[5] + f2 * cb[8];

    float r = sqrtf(v0 * v0 + v1 * v1 + v2 * v2 + 1e-8f);

    // mv = (rcell @ cell) @ vr  ; cv_k = cell[k,:]·v
    float cv0 = cb[0] * v0 + cb[1] * v1 + cb[2] * v2;
    float cv1 = cb[3] * v0 + cb[4] * v1 + cb[5] * v2;
    float cv2 = cb[6] * v0 + cb[7] * v1 + cb[8] * v2;
    float mv0 = rb[0] * cv0 + rb[1] * cv1 + rb[2] * cv2;
    float mv1 = rb[3] * cv0 + rb[4] * cv1 + rb[5] * cv2;
    float mv2 = rb[6] * cv0 + rb[7] * cv1 + rb[8] * cv2;

    // ---- bond-order features + d/dr tangent ----
    float h3[3], h3t[3];
    bop_calc(r, -0.077f, 1.39f, 6, h3[0], h3t[0]);
    bop_calc(r, -0.15f,  1.30f, 5, h3[1], h3t[1]);
    bop_calc(r, -0.30f,  1.25f, 4, h3[2], h3t[2]);

    // ---- MLP 1 (fm): 3 -> 9 -> (5x) 9 -> 3, sigmoid everywhere ----
    float h[9], ht[9];
    #pragma unroll
    for (int jj = 0; jj < 9; jj++) {
        float z = w[OFF_FM_BI + jj], zt = 0.0f;
        #pragma unroll
        for (int kk = 0; kk < 3; kk++) {
            float wv = w[OFF_FM_WI + kk * 9 + jj];
            z  += h3[kk]  * wv;
            zt += h3t[kk] * wv;
        }
        float s = sigf(z);
        h[jj]  = s;
        ht[jj] = s * (1.0f - s) * zt;
    }
    for (int l = 0; l < 5; l++) {
        const int wo = OFF_FM_W + l * 81, bo = OFF_FM_B + l * 9;
        float hn[9], hnt[9];
        #pragma unroll
        for (int jj = 0; jj < 9; jj++) {
            float z = w[bo + jj], zt = 0.0f;
            #pragma unroll
            for (int kk = 0; kk < 9; kk++) {
                float wv = w[wo + kk * 9 + jj];
                z  += h[kk]  * wv;
                zt += ht[kk] * wv;
            }
            float s = sigf(z);
            hn[jj]  = s;
            hnt[jj] = s * (1.0f - s) * zt;
        }
        #pragma unroll
        for (int jj = 0; jj < 9; jj++) { h[jj] = hn[jj]; ht[jj] = hnt[jj]; }
    }
    float bo3[3], bo3t[3];
    #pragma unroll
    for (int jj = 0; jj < 3; jj++) {
        float z = w[OFF_FM_BO + jj], zt = 0.0f;
        #pragma unroll
        for (int kk = 0; kk < 9; kk++) {
            float wv = w[OFF_FM_WO + kk * 3 + jj];
            z  += h[kk]  * wv;
            zt += ht[kk] * wv;
        }
        float s = sigf(z);
        bo3[jj]  = s;
        bo3t[jj] = s * (1.0f - s) * zt;
    }

    // ---- MLP 2 (fe): 3 -> 8 -> (5x) 8 -> 1 ----
    float g8[8], g8t[8];
    #pragma unroll
    for (int jj = 0; jj < 8; jj++) {
        float z = w[OFF_FE_BI + jj], zt = 0.0f;
        #pragma unroll
        for (int kk = 0; kk < 3; kk++) {
            float wv = w[OFF_FE_WI + kk * 8 + jj];
            z  += bo3[kk]  * wv;
            zt += bo3t[kk] * wv;
        }
        float s = sigf(z);
        g8[jj]  = s;
        g8t[jj] = s * (1.0f - s) * zt;
    }
    for (int l = 0; l < 5; l++) {
        const int wo = OFF_FE_W + l * 64, bo = OFF_FE_B + l * 8;
        float gn[8], gnt[8];
        #pragma unroll
        for (int jj = 0; jj < 8; jj++) {
            float z = w[bo + jj], zt = 0.0f;
            #pragma unroll
            for (int kk = 0; kk < 8; kk++) {
                float wv = w[wo + kk * 8 + jj];
                z  += g8[kk]  * wv;
                zt += g8t[kk] * wv;
            }
            float s = sigf(z);
            gn[jj]  = s;
            gnt[jj] = s * (1.0f - s) * zt;
        }
        #pragma unroll
        for (int jj = 0; jj < 8; jj++) { g8[jj] = gn[jj]; g8t[jj] = gnt[jj]; }
    }
    float z = w[OFF_FE_BO], zt = 0.0f;
    #pragma unroll
    for (int kk = 0; kk < 8; kk++) {
        float wv = w[OFF_FE_WO + kk];
        z  += g8[kk]  * wv;
        zt += g8t[kk] * wv;
    }
    float esi  = sigf(z);
    float esit = esi * (1.0f - esi) * zt;   // d(esi)/dr

    // ---- energy + force ----
    float D   = desi_p[0];
    float ebd = -D * esi;          // per-bond energy
    float g   = -D * esit;         // dE_bond/dr
    float inv_r = 1.0f / r;
    float G0 = g * mv0 * inv_r;    // dE/dx_i
    float G1 = g * mv1 * inv_r;
    float G2 = g * mv2 * inv_r;

    float* force = out + BB;
    float* fi = force + (size_t)(b * NN + ai) * 3;
    float* fj = force + (size_t)(b * NN + aj) * 3;
    atomicAdd(&fi[0], -G0);
    atomicAdd(&fi[1], -G1);
    atomicAdd(&fi[2], -G2);
    atomicAdd(&fj[0],  G0);
    atomicAdd(&fj[1],  G1);
    atomicAdd(&fj[2],  G2);

    // ---- per-block energy reduction (block is entirely within batch b) ----
    float e = ebd;
    #pragma unroll
    for (int off = 32; off > 0; off >>= 1) e += __shfl_down(e, off, 64);
    if ((tid & 63) == 0) esum[tid >> 6] = e;
    __syncthreads();
    if (tid == 0) atomicAdd(&out[b], esum[0] + esum[1] + esum[2] + esum[3]);
}

extern "C" void kernel_launch(void* const* d_in, const int* in_sizes, int n_in,
                              void* d_out, int out_size, void* d_ws, size_t ws_size,
                              hipStream_t stream)
{
    // zero E + force accumulators (harness poisons once, never re-poisons)
    hipMemsetAsync(d_out, 0, (size_t)out_size * sizeof(float), stream);

    dim3 grid(BB * (NBOND / 256));
    dim3 block(256);
    reaxff_bond_kernel<<<grid, block, 0, stream>>>(
        (const float*)d_in[0],  (const float*)d_in[1],  (const float*)d_in[2],
        (const float*)d_in[3],  (const float*)d_in[4],  (const float*)d_in[5],
        (const float*)d_in[6],  (const float*)d_in[7],  (const float*)d_in[8],
        (const float*)d_in[9],  (const float*)d_in[10], (const float*)d_in[11],
        (const float*)d_in[12], (const float*)d_in[13], (const float*)d_in[14],
        (const float*)d_in[15], (const int*)d_in[16],
        (float*)d_out);
}